// Round 6
// baseline (110.647 us; speedup 1.0000x reference)
//
#include <hip/hip_runtime.h>

#define B_ 2
#define S_ 2048
#define H_ 16
#define DQ_ 192
#define DV_ 128
// log2(e)/sqrt(192): folded into Q at hoist time
#define SCL2 0.10411163731422901f

typedef short short8 __attribute__((ext_vector_type(8)));
typedef float f32x4 __attribute__((ext_vector_type(4)));
typedef unsigned uint2v __attribute__((ext_vector_type(2)));

#define KG_BYTES ((size_t)25165824)   // B*H*S*DQ*2
#define VG_BYTES ((size_t)16777216)   // B*H*DV*S*2

__device__ __forceinline__ unsigned short f2bf(float f) {
  union { float f; unsigned u; } x; x.f = f;
  unsigned r = x.u + 0x7FFFu + ((x.u >> 16) & 1u);   // RNE
  return (unsigned short)(r >> 16);
}

__device__ __forceinline__ float hw_exp2(float x) {
  float r; asm("v_exp_f32 %0, %1" : "=v"(r) : "v"(x)); return r;
}
__device__ __forceinline__ unsigned cvtpk(float lo, float hi) {
  unsigned r; asm("v_cvt_pk_bf16_f32 %0, %1, %2" : "=v"(r) : "v"(lo), "v"(hi)); return r;
}
// lane<->lane+32 butterfly via VALU (permlane32_swap), ~8cy vs ~120cy ds_bpermute
__device__ __forceinline__ float pl32max(float x) {
  uint2v r = __builtin_amdgcn_permlane32_swap(__float_as_uint(x), __float_as_uint(x), false, false);
  return fmaxf(__uint_as_float(r[0]), __uint_as_float(r[1]));
}
__device__ __forceinline__ float pl32add(float x) {
  uint2v r = __builtin_amdgcn_permlane32_swap(__float_as_uint(x), __float_as_uint(x), false, false);
  return __uint_as_float(r[0]) + __uint_as_float(r[1]);
}

#define GLL16(src, dst) \
  __builtin_amdgcn_global_load_lds((const __attribute__((address_space(1))) void*)(src), \
                                   (__attribute__((address_space(3))) void*)(dst), 16, 0, 0)

// ---------------- pre-pass: K -> bf16, row-swizzled [bh][s][384B] ----------------
__global__ __launch_bounds__(256) void prep_k(const float* __restrict__ K,
                                              unsigned short* __restrict__ Kg) {
  int idx = blockIdx.x * 256 + threadIdx.x;
  int d4 = idx % 48; int r = idx / 48;
  int h = r % H_; r /= H_;
  int s = r % S_; int b = r / S_;
  float4 f = *(const float4*)(K + (size_t)((b * S_ + s) * H_ + h) * DQ_ + d4 * 4);
  ushort4 u; u.x = f2bf(f.x); u.y = f2bf(f.y); u.z = f2bf(f.z); u.w = f2bf(f.w);
  size_t rowb = (size_t)((b * H_ + h) * S_ + s) * (DQ_ * 2);
  int cb = (d4 * 8) ^ ((s & 7) << 4);
  *(ushort4*)((char*)Kg + rowb + cb) = u;
}

// ------- pre-pass: V -> bf16, transposed+swizzled 8KB tiles [bh][sb][tile] -------
__global__ __launch_bounds__(256) void prep_v(const float* __restrict__ V,
                                              unsigned short* __restrict__ Vg) {
  __shared__ float lv[32][132];
  int blk = blockIdx.x;
  int sb = blk & 63, bh = blk >> 6;
  int b = bh >> 4, h = bh & 15;
  int tid = threadIdx.x;
  #pragma unroll
  for (int i = 0; i < 4; ++i) {
    int idx = i * 256 + tid;
    int s_in = idx >> 5, d4 = idx & 31;
    float4 f = *(const float4*)(V + (size_t)((b * S_ + sb * 32 + s_in) * H_ + h) * DV_ + d4 * 4);
    lv[s_in][d4 * 4 + 0] = f.x; lv[s_in][d4 * 4 + 1] = f.y;
    lv[s_in][d4 * 4 + 2] = f.z; lv[s_in][d4 * 4 + 3] = f.w;
  }
  __syncthreads();
  char* base = (char*)Vg + (size_t)blk * 8192;
  #pragma unroll
  for (int j = 0; j < 2; ++j) {
    int ob = tid * 32 + j * 16;
    int row = ob >> 7, cb = ob & 127;
    int orig = cb ^ ((row & 7) << 4);
    int d = row * 2 + (orig >> 6);
    int s0 = (orig & 63) >> 1;
    short8 u;
    #pragma unroll
    for (int e = 0; e < 8; ++e) u[e] = (short)f2bf(lv[s0 + e][d]);
    *(short8*)(base + ob) = u;
  }
}

// ---------------- main: flash MLA, swapped QK^T, VALU softmax reduces ----------------
__launch_bounds__(256, 4)
__global__ void mla_fwd(const float* __restrict__ Q,
                        const unsigned short* __restrict__ Kg,
                        const unsigned short* __restrict__ Vg,
                        float* __restrict__ O) {
  // unified staging buffer: [buf][ K 12288B | V 8192B ] -> 40960B total, 4 blocks/CU
  __shared__ __align__(16) unsigned char SB[2][20480];

  const int tid  = threadIdx.x;
  const int wid  = tid >> 6;
  const int lane = tid & 63;
  const int l15  = lane & 15;
  const int g    = lane >> 4;

  // balanced-quad mapping: co-resident blocks get qtiles {31-j, j, 16+j, 15-j}
  const int i  = blockIdx.x;
  const int x  = i & 7;
  const int li = i >> 3;
  const int c  = li & 31;
  const int s  = li >> 5;
  const int j  = c & 7;
  const int t  = c >> 3;
  const int bh = x * 4 + t;
  const int qtile = (s == 0) ? (31 - j) : (s == 1) ? j : (s == 2) ? (16 + j) : (15 - j);
  const int b  = bh >> 4, h = bh & 15;
  const int q0w = qtile * 64 + wid * 16;

  const char* kg_bh = (const char*)Kg + (size_t)bh * S_ * (DQ_ * 2);
  const char* vg_bh = (const char*)Vg + (size_t)bh * 64 * 8192;

  // ---- hoist Q fragments, pre-scaled by SCL2 (B-operand of swapped QK^T) ----
  short8 aq[6];
  {
    const size_t qoff = (size_t)((b * S_ + (q0w + l15)) * H_ + h) * DQ_;
    #pragma unroll
    for (int d0 = 0; d0 < 6; ++d0) {
      const float* p = Q + qoff + d0 * 32 + g * 8;
      float4 f0 = *(const float4*)(p);
      float4 f1 = *(const float4*)(p + 4);
      short8 a;
      a[0] = f2bf(f0.x * SCL2); a[1] = f2bf(f0.y * SCL2);
      a[2] = f2bf(f0.z * SCL2); a[3] = f2bf(f0.w * SCL2);
      a[4] = f2bf(f1.x * SCL2); a[5] = f2bf(f1.y * SCL2);
      a[6] = f2bf(f1.z * SCL2); a[7] = f2bf(f1.w * SCL2);
      aq[d0] = a;
    }
  }

  f32x4 o[8];   // O^T: o[t][r] = O[dv=16t+4g+r][q=l15]
  #pragma unroll
  for (int t2 = 0; t2 < 8; ++t2) o[t2] = (f32x4)0.0f;
  float m = -1e30f, l = 0.0f;   // l: per-lane PARTIAL (reduced once in epilogue)

  const int kxor = (l15 & 7) << 4;
  const int g16  = g * 16;
  const int vlane = 12288 + (l15 >> 1) * 128 +
                    ((((l15 & 1) * 64) + g16) ^ (((l15 >> 1) & 7) << 4));
  const int sA = l15 + ((lane & 16) << 1);
  const int sB = sA + 16;
  const bool up = lane >= 32;

  const int ntiles = qtile * 2 + 2;

  // ---- persistent staging pointers: 5 chunks/wave, affine in kt ----
  const char* sp[5];
  int sdo[5], sst[5];
  #pragma unroll
  for (int ci = 0; ci < 5; ++ci) {
    int cc = wid * 5 + ci;
    if (cc < 12) { sp[ci] = kg_bh + cc * 1024 + lane * 16;        sdo[ci] = cc * 1024;          sst[ci] = 12288; }
    else         { sp[ci] = vg_bh + (cc - 12) * 1024 + lane * 16; sdo[ci] = 12288 + (cc - 12) * 1024; sst[ci] = 8192; }
  }

  #define STAGE(buf)                                         \
    do {                                                     \
      _Pragma("unroll")                                      \
      for (int ci = 0; ci < 5; ++ci) {                       \
        GLL16(sp[ci], &SB[buf][sdo[ci]]);                    \
        sp[ci] += sst[ci];                                   \
      }                                                      \
    } while (0)

  STAGE(0);
  __syncthreads();

  int cur = 0;
  for (int kt = 0; kt < ntiles; ++kt) {
    const int kbase = kt * 32;
    if (kt + 1 < ntiles) STAGE(cur ^ 1);

    // ---- QK^T swapped: C[k][q] = mfma(K-frag, Q-frag); scale pre-folded ----
    const char* k0 = (const char*)&SB[cur][0] + l15 * 384;
    const char* k1 = k0 + 16 * 384;
    f32x4 sa0 = (f32x4)0.0f, sa1 = (f32x4)0.0f;
    __builtin_amdgcn_s_setprio(1);
    #pragma unroll
    for (int d0 = 0; d0 < 6; ++d0) {
      const int col = (d0 * 64 + g16) ^ kxor;
      short8 b0 = *(const short8*)(k0 + col);
      sa0 = __builtin_amdgcn_mfma_f32_16x16x32_bf16(b0, aq[d0], sa0, 0, 0, 0);
      short8 b1 = *(const short8*)(k1 + col);
      sa1 = __builtin_amdgcn_mfma_f32_16x16x32_bf16(b1, aq[d0], sa1, 0, 0, 0);
    }
    __builtin_amdgcn_s_setprio(0);

    // ---- hoist first half of V fragments (latency hides under softmax) ----
    const char* vbp = (const char*)&SB[cur][0] + vlane;
    short8 vb0 = *(const short8*)(vbp);
    short8 vb1 = *(const short8*)(vbp + 1024);
    short8 vb2 = *(const short8*)(vbp + 2048);
    short8 vb3 = *(const short8*)(vbp + 3072);

    // ---- causal mask (wave-uniform skip except near diagonal) ----
    float p[8];
    #pragma unroll
    for (int r = 0; r < 4; ++r) { p[r] = sa0[r]; p[4 + r] = sa1[r]; }
    if (kbase + 31 > q0w) {
      const int rem = q0w + l15 - kbase - 4 * g;
      #pragma unroll
      for (int r = 0; r < 4; ++r) {
        if (r > rem)      p[r]     = -1e30f;
        if (16 + r > rem) p[4 + r] = -1e30f;
      }
    }

    // ---- online softmax: max reduce = 7 VALU + 1 shfl16 + 1 permlane32 ----
    float mx = fmaxf(fmaxf(fmaxf(p[0], p[1]), fmaxf(p[2], p[3])),
                     fmaxf(fmaxf(p[4], p[5]), fmaxf(p[6], p[7])));
    mx = fmaxf(mx, __shfl_xor(mx, 16));
    mx = pl32max(mx);
    if (__any(mx > m + 8.0f)) {          // defer-max
      float mn = fmaxf(m, mx);
      float al = hw_exp2(m - mn);
      #pragma unroll
      for (int t2 = 0; t2 < 8; ++t2) o[t2] *= al;
      l *= al; m = mn;
    }
    #pragma unroll
    for (int jj = 0; jj < 8; ++jj) p[jj] = hw_exp2(p[jj] - m);
    // per-lane partial row-sum only; cross-lane reduce deferred to epilogue
    l += ((p[0] + p[1]) + (p[2] + p[3])) + ((p[4] + p[5]) + (p[6] + p[7]));

    // ---- P -> B-fragment: cvt_pk + cross-lane exchange ----
    unsigned pk0 = cvtpk(p[0], p[1]);
    unsigned pk1 = cvtpk(p[2], p[3]);
    unsigned pk2 = cvtpk(p[4], p[5]);
    unsigned pk3 = cvtpk(p[6], p[7]);
    unsigned lo0 = __shfl(pk0, sA), hi0 = __shfl(pk2, sA);
    unsigned lo1 = __shfl(pk1, sA), hi1 = __shfl(pk3, sA);
    unsigned lo2 = __shfl(pk0, sB), hi2 = __shfl(pk2, sB);
    unsigned lo3 = __shfl(pk1, sB), hi3 = __shfl(pk3, sB);
    // second half of V fragments (latency hides under first PV MFMAs)
    short8 vb4 = *(const short8*)(vbp + 4096);
    short8 vb5 = *(const short8*)(vbp + 5120);
    short8 vb6 = *(const short8*)(vbp + 6144);
    short8 vb7 = *(const short8*)(vbp + 7168);
    union { unsigned u[4]; short8 s; } pb;
    pb.u[0] = up ? hi0 : lo0;
    pb.u[1] = up ? hi1 : lo1;
    pb.u[2] = up ? hi2 : lo2;
    pb.u[3] = up ? hi3 : lo3;

    // ---- PV swapped: O^T[dv][q] += mfma(Vt-frag, P-frag) ----
    __builtin_amdgcn_s_setprio(1);
    o[0] = __builtin_amdgcn_mfma_f32_16x16x32_bf16(vb0, pb.s, o[0], 0, 0, 0);
    o[1] = __builtin_amdgcn_mfma_f32_16x16x32_bf16(vb1, pb.s, o[1], 0, 0, 0);
    o[2] = __builtin_amdgcn_mfma_f32_16x16x32_bf16(vb2, pb.s, o[2], 0, 0, 0);
    o[3] = __builtin_amdgcn_mfma_f32_16x16x32_bf16(vb3, pb.s, o[3], 0, 0, 0);
    o[4] = __builtin_amdgcn_mfma_f32_16x16x32_bf16(vb4, pb.s, o[4], 0, 0, 0);
    o[5] = __builtin_amdgcn_mfma_f32_16x16x32_bf16(vb5, pb.s, o[5], 0, 0, 0);
    o[6] = __builtin_amdgcn_mfma_f32_16x16x32_bf16(vb6, pb.s, o[6], 0, 0, 0);
    o[7] = __builtin_amdgcn_mfma_f32_16x16x32_bf16(vb7, pb.s, o[7], 0, 0, 0);
    __builtin_amdgcn_s_setprio(0);

    __syncthreads();
    cur ^= 1;
  }

  // ---- epilogue: single cross-lane sum reduce, then store ----
  {
    float ll = l + __shfl_xor(l, 16);
    ll = pl32add(ll);
    const int q = q0w + l15;
    const float inv = 1.0f / ll;
    float* ob = O + (size_t)((b * S_ + q) * H_ + h) * DV_ + 4 * g;
    #pragma unroll
    for (int t2 = 0; t2 < 8; ++t2) {
      float4 st = { o[t2][0] * inv, o[t2][1] * inv, o[t2][2] * inv, o[t2][3] * inv };
      *(float4*)(ob + 16 * t2) = st;
    }
  }
  #undef STAGE
}

// ---------------- fallback (no-prep path) if ws too small ----------------
__launch_bounds__(256)
__global__ void mla_fwd_fb(const float* __restrict__ Q,
                           const float* __restrict__ K,
                           const float* __restrict__ V,
                           float* __restrict__ O) {
  __shared__ __align__(16) unsigned short Kl[2][32][200];
  __shared__ __align__(16) unsigned short Vt[2][128][40];
  __shared__ __align__(16) unsigned short Pl[4][16][40];
  const int tid = threadIdx.x, wid = tid >> 6, lane = tid & 63;
  const int l15 = lane & 15, g = lane >> 4;
  const int qtile = (int)gridDim.x - 1 - (int)blockIdx.x;
  const int bh = blockIdx.y, b = bh >> 4, h = bh & 15;
  const int q0w = qtile * 64 + wid * 16;
  const int krs = H_ * DQ_, vrs = H_ * DV_;
  short8 aq[6];
  {
    const int qoff = ((b * S_ + (q0w + l15)) * H_ + h) * DQ_;
    #pragma unroll
    for (int d0 = 0; d0 < 6; ++d0) {
      const float* p = Q + qoff + d0 * 32 + g * 8;
      float4 f0 = *(const float4*)(p); float4 f1 = *(const float4*)(p + 4);
      short8 a;
      a[0]=f2bf(f0.x); a[1]=f2bf(f0.y); a[2]=f2bf(f0.z); a[3]=f2bf(f0.w);
      a[4]=f2bf(f1.x); a[5]=f2bf(f1.y); a[6]=f2bf(f1.z); a[7]=f2bf(f1.w);
      aq[d0] = a;
    }
  }
  f32x4 o[8];
  #pragma unroll
  for (int t = 0; t < 8; ++t) o[t] = (f32x4)0.0f;
  float m[4], l[4];
  #pragma unroll
  for (int r = 0; r < 4; ++r) { m[r] = -1e30f; l[r] = 0.0f; }
  const int ntiles = qtile * 2 + 2;
  float4 kr[6], vr[4];
  {
    const float* Kb = K + ((b * S_) * H_ + h) * DQ_;
    #pragma unroll
    for (int i = 0; i < 6; ++i) { int idx = i*256+tid; int row = idx/48, c4 = idx%48;
      kr[i] = *(const float4*)(Kb + row*krs + c4*4); }
    const float* Vb = V + ((b * S_) * H_ + h) * DV_;
    #pragma unroll
    for (int i = 0; i < 4; ++i) { int idx = i*256+tid; int row = idx&31, c4 = idx>>5;
      vr[i] = *(const float4*)(Vb + row*vrs + c4*4); }
    #pragma unroll
    for (int i = 0; i < 6; ++i) { int idx = i*256+tid; int row = idx/48, c4 = idx%48;
      ushort4 u; u.x=f2bf(kr[i].x); u.y=f2bf(kr[i].y); u.z=f2bf(kr[i].z); u.w=f2bf(kr[i].w);
      *(ushort4*)&Kl[0][row][c4*4] = u; }
    #pragma unroll
    for (int i = 0; i < 4; ++i) { int idx = i*256+tid; int row = idx&31, c4 = idx>>5;
      Vt[0][c4*4+0][row]=f2bf(vr[i].x); Vt[0][c4*4+1][row]=f2bf(vr[i].y);
      Vt[0][c4*4+2][row]=f2bf(vr[i].z); Vt[0][c4*4+3][row]=f2bf(vr[i].w); }
  }
  __syncthreads();
  int cur = 0;
  for (int kt = 0; kt < ntiles; ++kt) {
    const int kbase = kt * 32;
    const bool pf = (kt + 1 < ntiles);
    if (pf) {
      const int nb = kbase + 32;
      const float* Kb = K + ((b*S_+nb)*H_ + h)*DQ_;
      #pragma unroll
      for (int i = 0; i < 6; ++i) { int idx = i*256+tid; int row = idx/48, c4 = idx%48;
        kr[i] = *(const float4*)(Kb + row*krs + c4*4); }
      const float* Vb = V + ((b*S_+nb)*H_ + h)*DV_;
      #pragma unroll
      for (int i = 0; i < 4; ++i) { int idx = i*256+tid; int row = idx&31, c4 = idx>>5;
        vr[i] = *(const float4*)(Vb + row*vrs + c4*4); }
    }
    f32x4 sa0 = (f32x4)0.0f, sa1 = (f32x4)0.0f;
    #pragma unroll
    for (int d0 = 0; d0 < 6; ++d0) {
      short8 b0 = *(const short8*)&Kl[cur][l15][d0*32 + g*8];
      sa0 = __builtin_amdgcn_mfma_f32_16x16x32_bf16(aq[d0], b0, sa0, 0, 0, 0);
      short8 b1 = *(const short8*)&Kl[cur][16+l15][d0*32 + g*8];
      sa1 = __builtin_amdgcn_mfma_f32_16x16x32_bf16(aq[d0], b1, sa1, 0, 0, 0);
    }
    float p0[4], p1[4];
    #pragma unroll
    for (int r = 0; r < 4; ++r) {
      const int qg = q0w + 4*g + r;
      float s0 = sa0[r]*SCL2, s1 = sa1[r]*SCL2;
      if (kbase + l15 > qg) s0 = -1e30f;
      if (kbase + 16 + l15 > qg) s1 = -1e30f;
      p0[r] = s0; p1[r] = s1;
    }
    #pragma unroll
    for (int r = 0; r < 4; ++r) {
      float rm = fmaxf(p0[r], p1[r]);
      #pragma unroll
      for (int off = 1; off < 16; off <<= 1) rm = fmaxf(rm, __shfl_xor(rm, off));
      float mn = fmaxf(m[r], rm);
      float alpha = exp2f(m[r] - mn); m[r] = mn;
      float e0 = exp2f(p0[r] - mn), e1 = exp2f(p1[r] - mn);
      p0[r] = e0; p1[r] = e1;
      float rsum = e0 + e1;
      #pragma unroll
      for (int off = 1; off < 16; off <<= 1) rsum += __shfl_xor(rsum, off);
      l[r] = l[r]*alpha + rsum;
      #pragma unroll
      for (int t = 0; t < 8; ++t) o[t][r] *= alpha;
    }
    #pragma unroll
    for (int r = 0; r < 4; ++r) {
      Pl[wid][4*g+r][l15]      = f2bf(p0[r]);
      Pl[wid][4*g+r][16+l15]   = f2bf(p1[r]);
    }
    short8 pa = *(const short8*)&Pl[wid][l15][g*8];
    #pragma unroll
    for (int t = 0; t < 8; ++t) {
      short8 vb = *(const short8*)&Vt[cur][t*16+l15][g*8];
      o[t] = __builtin_amdgcn_mfma_f32_16x16x32_bf16(pa, vb, o[t], 0, 0, 0);
    }
    if (pf) {
      #pragma unroll
      for (int i = 0; i < 6; ++i) { int idx = i*256+tid; int row = idx/48, c4 = idx%48;
        ushort4 u; u.x=f2bf(kr[i].x); u.y=f2bf(kr[i].y); u.z=f2bf(kr[i].z); u.w=f2bf(kr[i].w);
        *(ushort4*)&Kl[cur^1][row][c4*4] = u; }
      #pragma unroll
      for (int i = 0; i < 4; ++i) { int idx = i*256+tid; int row = idx&31, c4 = idx>>5;
        Vt[cur^1][c4*4+0][row]=f2bf(vr[i].x); Vt[cur^1][c4*4+1][row]=f2bf(vr[i].y);
        Vt[cur^1][c4*4+2][row]=f2bf(vr[i].z); Vt[cur^1][c4*4+3][row]=f2bf(vr[i].w); }
    }
    __syncthreads();
    cur ^= 1;
  }
  #pragma unroll
  for (int r = 0; r < 4; ++r) {
    const int qg = q0w + 4*g + r;
    const float inv = 1.0f / l[r];
    #pragma unroll
    for (int t = 0; t < 8; ++t)
      O[((b*S_+qg)*H_ + h)*DV_ + t*16 + l15] = o[t][r] * inv;
  }
}

extern "C" void kernel_launch(void* const* d_in, const int* in_sizes, int n_in,
                              void* d_out, int out_size, void* d_ws, size_t ws_size,
                              hipStream_t stream) {
  const float* q = (const float*)d_in[0];
  const float* k = (const float*)d_in[1];
  const float* v = (const float*)d_in[2];
  float* out = (float*)d_out;

  if (ws_size >= KG_BYTES + VG_BYTES) {
    unsigned short* Kg = (unsigned short*)d_ws;
    unsigned short* Vg = (unsigned short*)((char*)d_ws + KG_BYTES);
    prep_k<<<dim3((B_ * S_ * H_ * 48) / 256), dim3(256), 0, stream>>>(k, Kg);
    prep_v<<<dim3(B_ * H_ * 64), dim3(256), 0, stream>>>(v, Vg);
    mla_fwd<<<dim3(1024), dim3(256), 0, stream>>>(q, Kg, Vg, out);
  } else {
    dim3 grid(S_ / 64, B_ * H_);
    mla_fwd_fb<<<grid, dim3(256), 0, stream>>>(q, k, v, out);
  }
}

// Round 7
// 106.165 us; speedup vs baseline: 1.0422x; 1.0422x over previous
//
#include <hip/hip_runtime.h>

#define B_ 2
#define S_ 2048
#define H_ 16
#define DQ_ 192
#define DV_ 128
// log2(e)/sqrt(192): folded into Q at hoist time
#define SCL2 0.10411163731422901f

typedef short short8 __attribute__((ext_vector_type(8)));
typedef float f32x4 __attribute__((ext_vector_type(4)));
typedef unsigned uint2v __attribute__((ext_vector_type(2)));

#define KG_BYTES ((size_t)25165824)   // B*H*S*DQ*2
#define VG_BYTES ((size_t)16777216)   // B*H*DV*S*2

__device__ __forceinline__ unsigned short f2bf(float f) {
  union { float f; unsigned u; } x; x.f = f;
  unsigned r = x.u + 0x7FFFu + ((x.u >> 16) & 1u);   // RNE
  return (unsigned short)(r >> 16);
}

__device__ __forceinline__ float hw_exp2(float x) {
  float r; asm("v_exp_f32 %0, %1" : "=v"(r) : "v"(x)); return r;
}
__device__ __forceinline__ unsigned cvtpk(float lo, float hi) {
  unsigned r; asm("v_cvt_pk_bf16_f32 %0, %1, %2" : "=v"(r) : "v"(lo), "v"(hi)); return r;
}
// lane<->lane+32 butterfly via VALU (permlane32_swap)
__device__ __forceinline__ float pl32max(float x) {
  uint2v r = __builtin_amdgcn_permlane32_swap(__float_as_uint(x), __float_as_uint(x), false, false);
  return fmaxf(__uint_as_float(r[0]), __uint_as_float(r[1]));
}
__device__ __forceinline__ float pl32add(float x) {
  uint2v r = __builtin_amdgcn_permlane32_swap(__float_as_uint(x), __float_as_uint(x), false, false);
  return __uint_as_float(r[0]) + __uint_as_float(r[1]);
}

#define GLL16(src, dst) \
  __builtin_amdgcn_global_load_lds((const __attribute__((address_space(1))) void*)(src), \
                                   (__attribute__((address_space(3))) void*)(dst), 16, 0, 0)

// ---------------- pre-pass: K -> bf16, row-swizzled [bh][s][384B] ----------------
__global__ __launch_bounds__(256) void prep_k(const float* __restrict__ K,
                                              unsigned short* __restrict__ Kg) {
  int idx = blockIdx.x * 256 + threadIdx.x;
  int d4 = idx % 48; int r = idx / 48;
  int h = r % H_; r /= H_;
  int s = r % S_; int b = r / S_;
  float4 f = *(const float4*)(K + (size_t)((b * S_ + s) * H_ + h) * DQ_ + d4 * 4);
  ushort4 u; u.x = f2bf(f.x); u.y = f2bf(f.y); u.z = f2bf(f.z); u.w = f2bf(f.w);
  size_t rowb = (size_t)((b * H_ + h) * S_ + s) * (DQ_ * 2);
  int cb = (d4 * 8) ^ ((s & 7) << 4);
  *(ushort4*)((char*)Kg + rowb + cb) = u;
}

// ------- pre-pass: V -> bf16, transposed+swizzled 8KB tiles [bh][sb][tile] -------
__global__ __launch_bounds__(256) void prep_v(const float* __restrict__ V,
                                              unsigned short* __restrict__ Vg) {
  __shared__ float lv[32][132];
  int blk = blockIdx.x;
  int sb = blk & 63, bh = blk >> 6;
  int b = bh >> 4, h = bh & 15;
  int tid = threadIdx.x;
  #pragma unroll
  for (int i = 0; i < 4; ++i) {
    int idx = i * 256 + tid;
    int s_in = idx >> 5, d4 = idx & 31;
    float4 f = *(const float4*)(V + (size_t)((b * S_ + sb * 32 + s_in) * H_ + h) * DV_ + d4 * 4);
    lv[s_in][d4 * 4 + 0] = f.x; lv[s_in][d4 * 4 + 1] = f.y;
    lv[s_in][d4 * 4 + 2] = f.z; lv[s_in][d4 * 4 + 3] = f.w;
  }
  __syncthreads();
  char* base = (char*)Vg + (size_t)blk * 8192;
  #pragma unroll
  for (int j = 0; j < 2; ++j) {
    int ob = tid * 32 + j * 16;
    int row = ob >> 7, cb = ob & 127;
    int orig = cb ^ ((row & 7) << 4);
    int d = row * 2 + (orig >> 6);
    int s0 = (orig & 63) >> 1;
    short8 u;
    #pragma unroll
    for (int e = 0; e < 8; ++e) u[e] = (short)f2bf(lv[s0 + e][d]);
    *(short8*)(base + ob) = u;
  }
}

// ------- main: flash MLA, swapped QK^T, equal-work qtile pairs (zero tail) -------
__launch_bounds__(256, 2)
__global__ void mla_fwd(const float* __restrict__ Q,
                        const unsigned short* __restrict__ Kg,
                        const unsigned short* __restrict__ Vg,
                        float* __restrict__ O) {
  // unified staging buffer: [buf][ K 12288B | V 8192B ]
  __shared__ __align__(16) unsigned char SB[2][20480];

  const int tid  = threadIdx.x;
  const int wid  = tid >> 6;
  const int lane = tid & 63;
  const int l15  = lane & 15;
  const int g    = lane >> 4;

  // equal-work mapping: block processes qtile pair {31-j, j} -> 66 iters for ALL blocks
  const int i  = blockIdx.x;           // 0..511
  const int x  = i & 7;                // XCD
  const int li = i >> 3;               // 0..63
  const int j  = li & 15;
  const int bh = x * 4 + (li >> 4);
  const int b  = bh >> 4, h = bh & 15;

  const char* kg_bh = (const char*)Kg + (size_t)bh * S_ * (DQ_ * 2);
  const char* vg_bh = (const char*)Vg + (size_t)bh * 64 * 8192;

  // job-independent lane addressing
  const int kxor = (l15 & 7) << 4;
  const int g16  = g * 16;
  const int vlane = 12288 + (l15 >> 1) * 128 +
                    ((((l15 & 1) * 64) + g16) ^ (((l15 >> 1) & 7) << 4));
  const int sA = l15 + ((lane & 16) << 1);
  const int sB = sA + 16;
  const bool up = lane >= 32;

  #define STAGE(buf)                                         \
    do {                                                     \
      _Pragma("unroll")                                      \
      for (int ci = 0; ci < 5; ++ci) {                       \
        GLL16(sp[ci], &SB[buf][sdo[ci]]);                    \
        sp[ci] += sst[ci];                                   \
      }                                                      \
    } while (0)

  for (int job = 0; job < 2; ++job) {
    const int qtile = job ? j : (31 - j);
    const int q0w = qtile * 64 + wid * 16;

    // ---- hoist Q fragments, pre-scaled by SCL2 ----
    short8 aq[6];
    {
      const size_t qoff = (size_t)((b * S_ + (q0w + l15)) * H_ + h) * DQ_;
      #pragma unroll
      for (int d0 = 0; d0 < 6; ++d0) {
        const float* p = Q + qoff + d0 * 32 + g * 8;
        float4 f0 = *(const float4*)(p);
        float4 f1 = *(const float4*)(p + 4);
        short8 a;
        a[0] = f2bf(f0.x * SCL2); a[1] = f2bf(f0.y * SCL2);
        a[2] = f2bf(f0.z * SCL2); a[3] = f2bf(f0.w * SCL2);
        a[4] = f2bf(f1.x * SCL2); a[5] = f2bf(f1.y * SCL2);
        a[6] = f2bf(f1.z * SCL2); a[7] = f2bf(f1.w * SCL2);
        aq[d0] = a;
      }
    }

    f32x4 o[8];
    #pragma unroll
    for (int t2 = 0; t2 < 8; ++t2) o[t2] = (f32x4)0.0f;
    float m = -1e30f, l = 0.0f;

    const int ntiles = qtile * 2 + 2;

    // ---- persistent staging pointers (recomputed per job) ----
    const char* sp[5];
    int sdo[5], sst[5];
    #pragma unroll
    for (int ci = 0; ci < 5; ++ci) {
      int cc = wid * 5 + ci;
      if (cc < 12) { sp[ci] = kg_bh + cc * 1024 + lane * 16;        sdo[ci] = cc * 1024;                sst[ci] = 12288; }
      else         { sp[ci] = vg_bh + (cc - 12) * 1024 + lane * 16; sdo[ci] = 12288 + (cc - 12) * 1024; sst[ci] = 8192; }
    }

    STAGE(0);
    __syncthreads();

    int cur = 0;
    for (int kt = 0; kt < ntiles; ++kt) {
      const int kbase = kt * 32;
      if (kt + 1 < ntiles) STAGE(cur ^ 1);

      // ---- QK^T swapped: C[k][q] = mfma(K-frag, Q-frag); scale pre-folded ----
      const char* k0 = (const char*)&SB[cur][0] + l15 * 384;
      const char* k1 = k0 + 16 * 384;
      f32x4 sa0 = (f32x4)0.0f, sa1 = (f32x4)0.0f;
      __builtin_amdgcn_s_setprio(1);
      #pragma unroll
      for (int d0 = 0; d0 < 6; ++d0) {
        const int col = (d0 * 64 + g16) ^ kxor;
        short8 b0 = *(const short8*)(k0 + col);
        sa0 = __builtin_amdgcn_mfma_f32_16x16x32_bf16(b0, aq[d0], sa0, 0, 0, 0);
        short8 b1 = *(const short8*)(k1 + col);
        sa1 = __builtin_amdgcn_mfma_f32_16x16x32_bf16(b1, aq[d0], sa1, 0, 0, 0);
      }
      __builtin_amdgcn_s_setprio(0);

      // ---- hoist first half of V fragments ----
      const char* vbp = (const char*)&SB[cur][0] + vlane;
      short8 vb0 = *(const short8*)(vbp);
      short8 vb1 = *(const short8*)(vbp + 1024);
      short8 vb2 = *(const short8*)(vbp + 2048);
      short8 vb3 = *(const short8*)(vbp + 3072);

      // ---- causal mask (wave-uniform skip except near diagonal) ----
      float p[8];
      #pragma unroll
      for (int r = 0; r < 4; ++r) { p[r] = sa0[r]; p[4 + r] = sa1[r]; }
      if (kbase + 31 > q0w) {
        const int rem = q0w + l15 - kbase - 4 * g;
        #pragma unroll
        for (int r = 0; r < 4; ++r) {
          if (r > rem)      p[r]     = -1e30f;
          if (16 + r > rem) p[4 + r] = -1e30f;
        }
      }

      // ---- online softmax ----
      float mx = fmaxf(fmaxf(fmaxf(p[0], p[1]), fmaxf(p[2], p[3])),
                       fmaxf(fmaxf(p[4], p[5]), fmaxf(p[6], p[7])));
      mx = fmaxf(mx, __shfl_xor(mx, 16));
      mx = pl32max(mx);
      if (__any(mx > m + 8.0f)) {          // defer-max
        float mn = fmaxf(m, mx);
        float al = hw_exp2(m - mn);
        #pragma unroll
        for (int t2 = 0; t2 < 8; ++t2) o[t2] *= al;
        l *= al; m = mn;
      }
      #pragma unroll
      for (int jj = 0; jj < 8; ++jj) p[jj] = hw_exp2(p[jj] - m);
      l += ((p[0] + p[1]) + (p[2] + p[3])) + ((p[4] + p[5]) + (p[6] + p[7]));

      // ---- P -> B-fragment: cvt_pk + cross-lane exchange ----
      unsigned pk0 = cvtpk(p[0], p[1]);
      unsigned pk1 = cvtpk(p[2], p[3]);
      unsigned pk2 = cvtpk(p[4], p[5]);
      unsigned pk3 = cvtpk(p[6], p[7]);
      unsigned lo0 = __shfl(pk0, sA), hi0 = __shfl(pk2, sA);
      unsigned lo1 = __shfl(pk1, sA), hi1 = __shfl(pk3, sA);
      unsigned lo2 = __shfl(pk0, sB), hi2 = __shfl(pk2, sB);
      unsigned lo3 = __shfl(pk1, sB), hi3 = __shfl(pk3, sB);
      short8 vb4 = *(const short8*)(vbp + 4096);
      short8 vb5 = *(const short8*)(vbp + 5120);
      short8 vb6 = *(const short8*)(vbp + 6144);
      short8 vb7 = *(const short8*)(vbp + 7168);
      union { unsigned u[4]; short8 s; } pb;
      pb.u[0] = up ? hi0 : lo0;
      pb.u[1] = up ? hi1 : lo1;
      pb.u[2] = up ? hi2 : lo2;
      pb.u[3] = up ? hi3 : lo3;

      // ---- PV swapped: O^T[dv][q] += mfma(Vt-frag, P-frag) ----
      __builtin_amdgcn_s_setprio(1);
      o[0] = __builtin_amdgcn_mfma_f32_16x16x32_bf16(vb0, pb.s, o[0], 0, 0, 0);
      o[1] = __builtin_amdgcn_mfma_f32_16x16x32_bf16(vb1, pb.s, o[1], 0, 0, 0);
      o[2] = __builtin_amdgcn_mfma_f32_16x16x32_bf16(vb2, pb.s, o[2], 0, 0, 0);
      o[3] = __builtin_amdgcn_mfma_f32_16x16x32_bf16(vb3, pb.s, o[3], 0, 0, 0);
      o[4] = __builtin_amdgcn_mfma_f32_16x16x32_bf16(vb4, pb.s, o[4], 0, 0, 0);
      o[5] = __builtin_amdgcn_mfma_f32_16x16x32_bf16(vb5, pb.s, o[5], 0, 0, 0);
      o[6] = __builtin_amdgcn_mfma_f32_16x16x32_bf16(vb6, pb.s, o[6], 0, 0, 0);
      o[7] = __builtin_amdgcn_mfma_f32_16x16x32_bf16(vb7, pb.s, o[7], 0, 0, 0);
      __builtin_amdgcn_s_setprio(0);

      __syncthreads();
      cur ^= 1;
    }

    // ---- per-job epilogue: single cross-lane sum reduce, then store ----
    {
      float ll = l + __shfl_xor(l, 16);
      ll = pl32add(ll);
      const int q = q0w + l15;
      const float inv = 1.0f / ll;
      float* ob = O + (size_t)((b * S_ + q) * H_ + h) * DV_ + 4 * g;
      #pragma unroll
      for (int t2 = 0; t2 < 8; ++t2) {
        float4 st = { o[t2][0] * inv, o[t2][1] * inv, o[t2][2] * inv, o[t2][3] * inv };
        *(float4*)(ob + 16 * t2) = st;
      }
    }
  }
  #undef STAGE
}

// ---------------- fallback (no-prep path) if ws too small ----------------
__launch_bounds__(256)
__global__ void mla_fwd_fb(const float* __restrict__ Q,
                           const float* __restrict__ K,
                           const float* __restrict__ V,
                           float* __restrict__ O) {
  __shared__ __align__(16) unsigned short Kl[2][32][200];
  __shared__ __align__(16) unsigned short Vt[2][128][40];
  __shared__ __align__(16) unsigned short Pl[4][16][40];
  const int tid = threadIdx.x, wid = tid >> 6, lane = tid & 63;
  const int l15 = lane & 15, g = lane >> 4;
  const int qtile = (int)gridDim.x - 1 - (int)blockIdx.x;
  const int bh = blockIdx.y, b = bh >> 4, h = bh & 15;
  const int q0w = qtile * 64 + wid * 16;
  const int krs = H_ * DQ_, vrs = H_ * DV_;
  short8 aq[6];
  {
    const int qoff = ((b * S_ + (q0w + l15)) * H_ + h) * DQ_;
    #pragma unroll
    for (int d0 = 0; d0 < 6; ++d0) {
      const float* p = Q + qoff + d0 * 32 + g * 8;
      float4 f0 = *(const float4*)(p); float4 f1 = *(const float4*)(p + 4);
      short8 a;
      a[0]=f2bf(f0.x); a[1]=f2bf(f0.y); a[2]=f2bf(f0.z); a[3]=f2bf(f0.w);
      a[4]=f2bf(f1.x); a[5]=f2bf(f1.y); a[6]=f2bf(f1.z); a[7]=f2bf(f1.w);
      aq[d0] = a;
    }
  }
  f32x4 o[8];
  #pragma unroll
  for (int t = 0; t < 8; ++t) o[t] = (f32x4)0.0f;
  float m[4], l[4];
  #pragma unroll
  for (int r = 0; r < 4; ++r) { m[r] = -1e30f; l[r] = 0.0f; }
  const int ntiles = qtile * 2 + 2;
  float4 kr[6], vr[4];
  {
    const float* Kb = K + ((b * S_) * H_ + h) * DQ_;
    #pragma unroll
    for (int i = 0; i < 6; ++i) { int idx = i*256+tid; int row = idx/48, c4 = idx%48;
      kr[i] = *(const float4*)(Kb + row*krs + c4*4); }
    const float* Vb = V + ((b * S_) * H_ + h) * DV_;
    #pragma unroll
    for (int i = 0; i < 4; ++i) { int idx = i*256+tid; int row = idx&31, c4 = idx>>5;
      vr[i] = *(const float4*)(Vb + row*vrs + c4*4); }
    #pragma unroll
    for (int i = 0; i < 6; ++i) { int idx = i*256+tid; int row = idx/48, c4 = idx%48;
      ushort4 u; u.x=f2bf(kr[i].x); u.y=f2bf(kr[i].y); u.z=f2bf(kr[i].z); u.w=f2bf(kr[i].w);
      *(ushort4*)&Kl[0][row][c4*4] = u; }
    #pragma unroll
    for (int i = 0; i < 4; ++i) { int idx = i*256+tid; int row = idx&31, c4 = idx>>5;
      Vt[0][c4*4+0][row]=f2bf(vr[i].x); Vt[0][c4*4+1][row]=f2bf(vr[i].y);
      Vt[0][c4*4+2][row]=f2bf(vr[i].z); Vt[0][c4*4+3][row]=f2bf(vr[i].w); }
  }
  __syncthreads();
  int cur = 0;
  for (int kt = 0; kt < ntiles; ++kt) {
    const int kbase = kt * 32;
    const bool pf = (kt + 1 < ntiles);
    if (pf) {
      const int nb = kbase + 32;
      const float* Kb = K + ((b*S_+nb)*H_ + h)*DQ_;
      #pragma unroll
      for (int i = 0; i < 6; ++i) { int idx = i*256+tid; int row = idx/48, c4 = idx%48;
        kr[i] = *(const float4*)(Kb + row*krs + c4*4); }
      const float* Vb = V + ((b*S_+nb)*H_ + h)*DV_;
      #pragma unroll
      for (int i = 0; i < 4; ++i) { int idx = i*256+tid; int row = idx&31, c4 = idx>>5;
        vr[i] = *(const float4*)(Vb + row*vrs + c4*4); }
    }
    f32x4 sa0 = (f32x4)0.0f, sa1 = (f32x4)0.0f;
    #pragma unroll
    for (int d0 = 0; d0 < 6; ++d0) {
      short8 b0 = *(const short8*)&Kl[cur][l15][d0*32 + g*8];
      sa0 = __builtin_amdgcn_mfma_f32_16x16x32_bf16(aq[d0], b0, sa0, 0, 0, 0);
      short8 b1 = *(const short8*)&Kl[cur][16+l15][d0*32 + g*8];
      sa1 = __builtin_amdgcn_mfma_f32_16x16x32_bf16(aq[d0], b1, sa1, 0, 0, 0);
    }
    float p0[4], p1[4];
    #pragma unroll
    for (int r = 0; r < 4; ++r) {
      const int qg = q0w + 4*g + r;
      float s0 = sa0[r]*SCL2, s1 = sa1[r]*SCL2;
      if (kbase + l15 > qg) s0 = -1e30f;
      if (kbase + 16 + l15 > qg) s1 = -1e30f;
      p0[r] = s0; p1[r] = s1;
    }
    #pragma unroll
    for (int r = 0; r < 4; ++r) {
      float rm = fmaxf(p0[r], p1[r]);
      #pragma unroll
      for (int off = 1; off < 16; off <<= 1) rm = fmaxf(rm, __shfl_xor(rm, off));
      float mn = fmaxf(m[r], rm);
      float alpha = exp2f(m[r] - mn); m[r] = mn;
      float e0 = exp2f(p0[r] - mn), e1 = exp2f(p1[r] - mn);
      p0[r] = e0; p1[r] = e1;
      float rsum = e0 + e1;
      #pragma unroll
      for (int off = 1; off < 16; off <<= 1) rsum += __shfl_xor(rsum, off);
      l[r] = l[r]*alpha + rsum;
      #pragma unroll
      for (int t = 0; t < 8; ++t) o[t][r] *= alpha;
    }
    #pragma unroll
    for (int r = 0; r < 4; ++r) {
      Pl[wid][4*g+r][l15]      = f2bf(p0[r]);
      Pl[wid][4*g+r][16+l15]   = f2bf(p1[r]);
    }
    short8 pa = *(const short8*)&Pl[wid][l15][g*8];
    #pragma unroll
    for (int t = 0; t < 8; ++t) {
      short8 vb = *(const short8*)&Vt[cur][t*16+l15][g*8];
      o[t] = __builtin_amdgcn_mfma_f32_16x16x32_bf16(pa, vb, o[t], 0, 0, 0);
    }
    if (pf) {
      #pragma unroll
      for (int i = 0; i < 6; ++i) { int idx = i*256+tid; int row = idx/48, c4 = idx%48;
        ushort4 u; u.x=f2bf(kr[i].x); u.y=f2bf(kr[i].y); u.z=f2bf(kr[i].z); u.w=f2bf(kr[i].w);
        *(ushort4*)&Kl[cur^1][row][c4*4] = u; }
      #pragma unroll
      for (int i = 0; i < 4; ++i) { int idx = i*256+tid; int row = idx&31, c4 = idx>>5;
        Vt[cur^1][c4*4+0][row]=f2bf(vr[i].x); Vt[cur^1][c4*4+1][row]=f2bf(vr[i].y);
        Vt[cur^1][c4*4+2][row]=f2bf(vr[i].z); Vt[cur^1][c4*4+3][row]=f2bf(vr[i].w); }
    }
    __syncthreads();
    cur ^= 1;
  }
  #pragma unroll
  for (int r = 0; r < 4; ++r) {
    const int qg = q0w + 4*g + r;
    const float inv = 1.0f / l[r];
    #pragma unroll
    for (int t = 0; t < 8; ++t)
      O[((b*S_+qg)*H_ + h)*DV_ + t*16 + l15] = o[t][r] * inv;
  }
}

extern "C" void kernel_launch(void* const* d_in, const int* in_sizes, int n_in,
                              void* d_out, int out_size, void* d_ws, size_t ws_size,
                              hipStream_t stream) {
  const float* q = (const float*)d_in[0];
  const float* k = (const float*)d_in[1];
  const float* v = (const float*)d_in[2];
  float* out = (float*)d_out;

  if (ws_size >= KG_BYTES + VG_BYTES) {
    unsigned short* Kg = (unsigned short*)d_ws;
    unsigned short* Vg = (unsigned short*)((char*)d_ws + KG_BYTES);
    prep_k<<<dim3((B_ * S_ * H_ * 48) / 256), dim3(256), 0, stream>>>(k, Kg);
    prep_v<<<dim3(B_ * H_ * 64), dim3(256), 0, stream>>>(v, Vg);
    mla_fwd<<<dim3(512), dim3(256), 0, stream>>>(q, Kg, Vg, out);
  } else {
    dim3 grid(S_ / 64, B_ * H_);
    mla_fwd_fb<<<grid, dim3(256), 0, stream>>>(q, k, v, out);
  }
}

// Round 8
// 94.971 us; speedup vs baseline: 1.1651x; 1.1179x over previous
//
#include <hip/hip_runtime.h>

#define B_ 2
#define S_ 2048
#define H_ 16
#define DQ_ 192
#define DV_ 128
// log2(e)/sqrt(192): folded into Q at hoist time
#define SCL2 0.10411163731422901f

typedef short short8 __attribute__((ext_vector_type(8)));
typedef float f32x4 __attribute__((ext_vector_type(4)));
typedef float f32x16 __attribute__((ext_vector_type(16)));
typedef unsigned uint2v __attribute__((ext_vector_type(2)));

#define KG_BYTES ((size_t)25165824)   // B*H*S*DQ*2
#define VG_BYTES ((size_t)16777216)   // B*H*DV*S*2

__device__ __forceinline__ unsigned short f2bf(float f) {
  union { float f; unsigned u; } x; x.f = f;
  unsigned r = x.u + 0x7FFFu + ((x.u >> 16) & 1u);   // RNE
  return (unsigned short)(r >> 16);
}

__device__ __forceinline__ float hw_exp2(float x) {
  float r; asm("v_exp_f32 %0, %1" : "=v"(r) : "v"(x)); return r;
}
__device__ __forceinline__ unsigned cvtpk(float lo, float hi) {
  unsigned r; asm("v_cvt_pk_bf16_f32 %0, %1, %2" : "=v"(r) : "v"(lo), "v"(hi)); return r;
}
// lane<->lane+32 butterfly via VALU
__device__ __forceinline__ float pl32max(float x) {
  uint2v r = __builtin_amdgcn_permlane32_swap(__float_as_uint(x), __float_as_uint(x), false, false);
  return fmaxf(__uint_as_float(r[0]), __uint_as_float(r[1]));
}
__device__ __forceinline__ float pl32add(float x) {
  uint2v r = __builtin_amdgcn_permlane32_swap(__float_as_uint(x), __float_as_uint(x), false, false);
  return __uint_as_float(r[0]) + __uint_as_float(r[1]);
}

#define GLL16(src, dst) \
  __builtin_amdgcn_global_load_lds((const __attribute__((address_space(1))) void*)(src), \
                                   (__attribute__((address_space(3))) void*)(dst), 16, 0, 0)

// ---------------- pre-pass: K -> bf16, row-swizzled [bh][s][384B] ----------------
__global__ __launch_bounds__(256) void prep_k(const float* __restrict__ K,
                                              unsigned short* __restrict__ Kg) {
  int idx = blockIdx.x * 256 + threadIdx.x;
  int d4 = idx % 48; int r = idx / 48;
  int h = r % H_; r /= H_;
  int s = r % S_; int b = r / S_;
  float4 f = *(const float4*)(K + (size_t)((b * S_ + s) * H_ + h) * DQ_ + d4 * 4);
  ushort4 u; u.x = f2bf(f.x); u.y = f2bf(f.y); u.z = f2bf(f.z); u.w = f2bf(f.w);
  size_t rowb = (size_t)((b * H_ + h) * S_ + s) * (DQ_ * 2);
  int cb = (d4 * 8) ^ ((s & 7) << 4);
  *(ushort4*)((char*)Kg + rowb + cb) = u;
}

// -- pre-pass: V -> bf16 V^T 16KB tiles [bh][tile64]: byte = (dv>>1)*256 +
//    (((dv&1)*128 + k*2) ^ (((dv>>1)&15)<<4))  (4-bit XOR within pow2 pair-row) --
__global__ __launch_bounds__(256) void prep_v(const float* __restrict__ V,
                                              unsigned short* __restrict__ Vg) {
  __shared__ float lv[64][132];
  int blk = blockIdx.x;                 // bh*32 + tile
  int tile = blk & 31, bh = blk >> 5;
  int b = bh >> 4, h = bh & 15;
  int tid = threadIdx.x;
  #pragma unroll
  for (int it = 0; it < 8; ++it) {
    int idx = it * 256 + tid;           // 0..2047
    int s_in = idx >> 5, d4 = idx & 31;
    float4 f = *(const float4*)(V + (size_t)((b * S_ + tile * 64 + s_in) * H_ + h) * DV_ + d4 * 4);
    lv[s_in][d4 * 4 + 0] = f.x; lv[s_in][d4 * 4 + 1] = f.y;
    lv[s_in][d4 * 4 + 2] = f.z; lv[s_in][d4 * 4 + 3] = f.w;
  }
  __syncthreads();
  char* base = (char*)Vg + (size_t)blk * 16384;
  #pragma unroll
  for (int it = 0; it < 4; ++it) {
    int ch = it * 256 + tid;            // 0..1023 16B chunks
    int pr = ch >> 4, ci = ch & 15;
    int orig = ci ^ (pr & 15);          // un-swizzle
    int dv = pr * 2 + (orig >> 3);
    int k0 = (orig & 7) * 8;
    short8 u;
    #pragma unroll
    for (int e = 0; e < 8; ++e) u[e] = (short)f2bf(lv[k0 + e][dv]);
    *(short8*)(base + ch * 16) = u;     // linear write ✓
  }
}

// ------- main: flash MLA, 32x32x16 MFMA, 32q/wave, KVBLK=64, VALU-only softmax -------
__launch_bounds__(256, 2)
__global__ void mla_fwd(const float* __restrict__ Q,
                        const unsigned short* __restrict__ Kg,
                        const unsigned short* __restrict__ Vg,
                        float* __restrict__ O) {
  // [buf][ K 24KB (64 rows x 384B) | V 16KB ] = 40KB x 2 = 80KB -> 2 blocks/CU
  __shared__ __align__(16) unsigned char SB[2][40960];

  const int tid  = threadIdx.x;
  const int wid  = tid >> 6;
  const int lane = tid & 63;
  const int l31  = lane & 31;
  const int hi   = lane >> 5;
  const int hi16 = hi * 16;

  // CU-pair balanced mapping: slot c gets {15-jj, jj} (rounds 0/1), same bh; sum=36 tiles
  const int i  = blockIdx.x;           // 0..511
  const int x  = i & 7;                // XCD
  const int li = i >> 3;               // 0..63
  const int r_ = li >> 5;              // round
  const int c  = li & 31;              // CU slot
  const int bh = x * 4 + (c >> 3);
  const int jj = c & 7;
  const int qtile = r_ ? jj : (15 - jj);
  const int b  = bh >> 4, h = bh & 15;

  const char* kg_bh = (const char*)Kg + (size_t)bh * S_ * (DQ_ * 2);
  const char* vg_bh = (const char*)Vg + (size_t)bh * 32 * 16384;

  const int wq0 = qtile * 128 + wid * 32;   // wave's q base
  const int qln = wq0 + l31;                // this lane's q

  // ---- hoist Q B-fragments (pre-scaled): qf[d0] = Q[qln][d0*16 + hi*8 + j] ----
  short8 qf[12];
  {
    const size_t qoff = (size_t)((b * S_ + qln) * H_ + h) * DQ_;
    #pragma unroll
    for (int d0 = 0; d0 < 12; ++d0) {
      const float* p = Q + qoff + d0 * 16 + hi * 8;
      float4 f0 = *(const float4*)(p);
      float4 f1 = *(const float4*)(p + 4);
      short8 a;
      a[0] = f2bf(f0.x * SCL2); a[1] = f2bf(f0.y * SCL2);
      a[2] = f2bf(f0.z * SCL2); a[3] = f2bf(f0.w * SCL2);
      a[4] = f2bf(f1.x * SCL2); a[5] = f2bf(f1.y * SCL2);
      a[6] = f2bf(f1.z * SCL2); a[7] = f2bf(f1.w * SCL2);
      qf[d0] = a;
    }
  }

  f32x16 o[4];   // O^T: o[t2] reg r -> dv = t2*32 + (r&3)+8*(r>>2)+4*hi, q = qln
  #pragma unroll
  for (int t2 = 0; t2 < 4; ++t2) o[t2] = (f32x16)0.0f;
  float m = -1e30f, l = 0.0f;

  // K read swizzle + V read offsets (job-invariant)
  const int kxor = (lane & 7) << 4;
  const int prl  = l31 >> 1;
  const int nb_  = (lane & 1) * 8 + hi;
  int voff[2][2];
  #pragma unroll
  for (int kh = 0; kh < 2; ++kh)
    #pragma unroll
    for (int ks = 0; ks < 2; ++ks) {
      int n = nb_ + kh * 4 + ks * 2;
      voff[kh][ks] = prl * 256 + ((n ^ prl) << 4);
    }

  const int ntiles = 2 * qtile + 2;

  // staging: 40 x 1KB chunks (K 0..23, V 24..39), 10 per wave
  const char* kS = kg_bh + wid * 10240 + lane * 16;
  const char* vS = vg_bh - 24576 + wid * 10240 + lane * 16;

  #define STAGE(buf)                                                       \
    do {                                                                   \
      _Pragma("unroll")                                                    \
      for (int ci = 0; ci < 10; ++ci) {                                    \
        const int cc = wid * 10 + ci;                                      \
        const char* src = (cc < 24) ? (kS + ci * 1024) : (vS + ci * 1024); \
        GLL16(src, &SB[buf][cc * 1024]);                                   \
      }                                                                    \
    } while (0)

  #define HALF(S, KH)                                                             \
    {                                                                             \
      const int khb = kbase + (KH) * 32;                                          \
      if (khb <= wq0 + 31) {                                                      \
        float p_[16];                                                             \
        _Pragma("unroll") for (int r = 0; r < 16; ++r) p_[r] = S[r];              \
        if (khb + 31 > wq0) {                                                     \
          const int rem = qln - khb - 4 * hi;                                     \
          _Pragma("unroll") for (int r = 0; r < 16; ++r) {                        \
            const int kof = (r & 3) + 8 * (r >> 2);                               \
            if (kof > rem) p_[r] = -1e30f;                                        \
          }                                                                       \
        }                                                                         \
        float mx = p_[0];                                                         \
        _Pragma("unroll") for (int r = 1; r < 16; ++r) mx = fmaxf(mx, p_[r]);     \
        mx = pl32max(mx);                                                         \
        if (__any(mx > m + 8.0f)) {                                               \
          float mn = fmaxf(m, mx);                                                \
          float al = hw_exp2(m - mn);                                             \
          _Pragma("unroll") for (int t2 = 0; t2 < 4; ++t2) o[t2] *= al;           \
          l *= al; m = mn;                                                        \
        }                                                                         \
        _Pragma("unroll") for (int r = 0; r < 16; ++r) p_[r] = hw_exp2(p_[r] - m);\
        float sum_ = 0.0f;                                                        \
        _Pragma("unroll") for (int r = 0; r < 16; ++r) sum_ += p_[r];             \
        l += sum_;                                                                \
        unsigned a_ = cvtpk(p_[0], p_[1]),   b2_ = cvtpk(p_[2], p_[3]);           \
        unsigned c_ = cvtpk(p_[4], p_[5]),   d_  = cvtpk(p_[6], p_[7]);           \
        unsigned e_ = cvtpk(p_[8], p_[9]),   f_  = cvtpk(p_[10], p_[11]);         \
        unsigned g_ = cvtpk(p_[12], p_[13]), h_  = cvtpk(p_[14], p_[15]);         \
        uint2v s02 = __builtin_amdgcn_permlane32_swap(a_, c_, false, false);      \
        uint2v s13 = __builtin_amdgcn_permlane32_swap(b2_, d_, false, false);     \
        uint2v s46 = __builtin_amdgcn_permlane32_swap(e_, g_, false, false);      \
        uint2v s57 = __builtin_amdgcn_permlane32_swap(f_, h_, false, false);      \
        union { unsigned u[4]; short8 s; } pb0, pb1;                              \
        pb0.u[0] = s02[0]; pb0.u[1] = s13[0]; pb0.u[2] = s02[1]; pb0.u[3] = s13[1];\
        pb1.u[0] = s46[0]; pb1.u[1] = s57[0]; pb1.u[2] = s46[1]; pb1.u[3] = s57[1];\
        __builtin_amdgcn_s_setprio(1);                                            \
        _Pragma("unroll") for (int t2 = 0; t2 < 4; ++t2) {                        \
          short8 va0 = *(const short8*)(vbb + t2 * 4096 + voff[KH][0]);           \
          o[t2] = __builtin_amdgcn_mfma_f32_32x32x16_bf16(va0, pb0.s, o[t2], 0, 0, 0); \
          short8 va1 = *(const short8*)(vbb + t2 * 4096 + voff[KH][1]);           \
          o[t2] = __builtin_amdgcn_mfma_f32_32x32x16_bf16(va1, pb1.s, o[t2], 0, 0, 0); \
        }                                                                         \
        __builtin_amdgcn_s_setprio(0);                                            \
      }                                                                           \
    }

  STAGE(0); kS += 24576; vS += 16384;
  __syncthreads();

  int cur = 0;
  for (int kt = 0; kt < ntiles; ++kt) {
    const int kbase = kt * 64;
    if (kt + 1 < ntiles) { STAGE(cur ^ 1); kS += 24576; vS += 16384; }

    const unsigned char* kb  = SB[cur];
    const unsigned char* vbb = SB[cur] + 24576;
    const bool active = (kbase <= wq0 + 31);

    if (active) {
      // ---- QK^T swapped: C[k][q] = mfma(K-frag, Q-frag), both 32k halves ----
      const char* kr0 = (const char*)kb + l31 * 384;
      const char* kr1 = kr0 + 32 * 384;
      f32x16 s0 = (f32x16)0.0f, s1 = (f32x16)0.0f;
      __builtin_amdgcn_s_setprio(1);
      #pragma unroll
      for (int d0 = 0; d0 < 12; ++d0) {
        const int col = (d0 * 32 + hi16) ^ kxor;
        s0 = __builtin_amdgcn_mfma_f32_32x32x16_bf16(*(const short8*)(kr0 + col), qf[d0], s0, 0, 0, 0);
        s1 = __builtin_amdgcn_mfma_f32_32x32x16_bf16(*(const short8*)(kr1 + col), qf[d0], s1, 0, 0, 0);
      }
      __builtin_amdgcn_s_setprio(0);

      HALF(s0, 0)
      HALF(s1, 1)
    }

    __syncthreads();
    cur ^= 1;
  }

  // ---- epilogue: pair sum-reduce, store O[q][dv] as float4s ----
  {
    float ll = pl32add(l);
    const float inv = 1.0f / ll;
    float* ob = O + (size_t)((b * S_ + qln) * H_ + h) * DV_;
    #pragma unroll
    for (int t2 = 0; t2 < 4; ++t2) {
      #pragma unroll
      for (int rr = 0; rr < 4; ++rr) {
        float4 st = { o[t2][rr * 4 + 0] * inv, o[t2][rr * 4 + 1] * inv,
                      o[t2][rr * 4 + 2] * inv, o[t2][rr * 4 + 3] * inv };
        *(float4*)(ob + t2 * 32 + rr * 8 + hi * 4) = st;
      }
    }
  }
  #undef STAGE
  #undef HALF
}

// ---------------- fallback (no-prep path) if ws too small ----------------
__launch_bounds__(256)
__global__ void mla_fwd_fb(const float* __restrict__ Q,
                           const float* __restrict__ K,
                           const float* __restrict__ V,
                           float* __restrict__ O) {
  __shared__ __align__(16) unsigned short Kl[2][32][200];
  __shared__ __align__(16) unsigned short Vt[2][128][40];
  __shared__ __align__(16) unsigned short Pl[4][16][40];
  const int tid = threadIdx.x, wid = tid >> 6, lane = tid & 63;
  const int l15 = lane & 15, g = lane >> 4;
  const int qtile = (int)gridDim.x - 1 - (int)blockIdx.x;
  const int bh = blockIdx.y, b = bh >> 4, h = bh & 15;
  const int q0w = qtile * 64 + wid * 16;
  const int krs = H_ * DQ_, vrs = H_ * DV_;
  short8 aq[6];
  {
    const int qoff = ((b * S_ + (q0w + l15)) * H_ + h) * DQ_;
    #pragma unroll
    for (int d0 = 0; d0 < 6; ++d0) {
      const float* p = Q + qoff + d0 * 32 + g * 8;
      float4 f0 = *(const float4*)(p); float4 f1 = *(const float4*)(p + 4);
      short8 a;
      a[0]=f2bf(f0.x); a[1]=f2bf(f0.y); a[2]=f2bf(f0.z); a[3]=f2bf(f0.w);
      a[4]=f2bf(f1.x); a[5]=f2bf(f1.y); a[6]=f2bf(f1.z); a[7]=f2bf(f1.w);
      aq[d0] = a;
    }
  }
  f32x4 o[8];
  #pragma unroll
  for (int t = 0; t < 8; ++t) o[t] = (f32x4)0.0f;
  float m[4], l[4];
  #pragma unroll
  for (int r = 0; r < 4; ++r) { m[r] = -1e30f; l[r] = 0.0f; }
  const int ntiles = qtile * 2 + 2;
  float4 kr[6], vr[4];
  {
    const float* Kb = K + ((b * S_) * H_ + h) * DQ_;
    #pragma unroll
    for (int i = 0; i < 6; ++i) { int idx = i*256+tid; int row = idx/48, c4 = idx%48;
      kr[i] = *(const float4*)(Kb + row*krs + c4*4); }
    const float* Vb = V + ((b * S_) * H_ + h) * DV_;
    #pragma unroll
    for (int i = 0; i < 4; ++i) { int idx = i*256+tid; int row = idx&31, c4 = idx>>5;
      vr[i] = *(const float4*)(Vb + row*vrs + c4*4); }
    #pragma unroll
    for (int i = 0; i < 6; ++i) { int idx = i*256+tid; int row = idx/48, c4 = idx%48;
      ushort4 u; u.x=f2bf(kr[i].x); u.y=f2bf(kr[i].y); u.z=f2bf(kr[i].z); u.w=f2bf(kr[i].w);
      *(ushort4*)&Kl[0][row][c4*4] = u; }
    #pragma unroll
    for (int i = 0; i < 4; ++i) { int idx = i*256+tid; int row = idx&31, c4 = idx>>5;
      Vt[0][c4*4+0][row]=f2bf(vr[i].x); Vt[0][c4*4+1][row]=f2bf(vr[i].y);
      Vt[0][c4*4+2][row]=f2bf(vr[i].z); Vt[0][c4*4+3][row]=f2bf(vr[i].w); }
  }
  __syncthreads();
  int cur = 0;
  for (int kt = 0; kt < ntiles; ++kt) {
    const int kbase = kt * 32;
    const bool pf = (kt + 1 < ntiles);
    if (pf) {
      const int nb = kbase + 32;
      const float* Kb = K + ((b*S_+nb)*H_ + h)*DQ_;
      #pragma unroll
      for (int i = 0; i < 6; ++i) { int idx = i*256+tid; int row = idx/48, c4 = idx%48;
        kr[i] = *(const float4*)(Kb + row*krs + c4*4); }
      const float* Vb = V + ((b*S_+nb)*H_ + h)*DV_;
      #pragma unroll
      for (int i = 0; i < 4; ++i) { int idx = i*256+tid; int row = idx&31, c4 = idx>>5;
        vr[i] = *(const float4*)(Vb + row*vrs + c4*4); }
    }
    f32x4 sa0 = (f32x4)0.0f, sa1 = (f32x4)0.0f;
    #pragma unroll
    for (int d0 = 0; d0 < 6; ++d0) {
      short8 b0 = *(const short8*)&Kl[cur][l15][d0*32 + g*8];
      sa0 = __builtin_amdgcn_mfma_f32_16x16x32_bf16(aq[d0], b0, sa0, 0, 0, 0);
      short8 b1 = *(const short8*)&Kl[cur][16+l15][d0*32 + g*8];
      sa1 = __builtin_amdgcn_mfma_f32_16x16x32_bf16(aq[d0], b1, sa1, 0, 0, 0);
    }
    float p0[4], p1[4];
    #pragma unroll
    for (int r = 0; r < 4; ++r) {
      const int qg = q0w + 4*g + r;
      float s0 = sa0[r]*SCL2, s1 = sa1[r]*SCL2;
      if (kbase + l15 > qg) s0 = -1e30f;
      if (kbase + 16 + l15 > qg) s1 = -1e30f;
      p0[r] = s0; p1[r] = s1;
    }
    #pragma unroll
    for (int r = 0; r < 4; ++r) {
      float rm = fmaxf(p0[r], p1[r]);
      #pragma unroll
      for (int off = 1; off < 16; off <<= 1) rm = fmaxf(rm, __shfl_xor(rm, off));
      float mn = fmaxf(m[r], rm);
      float alpha = exp2f(m[r] - mn); m[r] = mn;
      float e0 = exp2f(p0[r] - mn), e1 = exp2f(p1[r] - mn);
      p0[r] = e0; p1[r] = e1;
      float rsum = e0 + e1;
      #pragma unroll
      for (int off = 1; off < 16; off <<= 1) rsum += __shfl_xor(rsum, off);
      l[r] = l[r]*alpha + rsum;
      #pragma unroll
      for (int t = 0; t < 8; ++t) o[t][r] *= alpha;
    }
    #pragma unroll
    for (int r = 0; r < 4; ++r) {
      Pl[wid][4*g+r][l15]      = f2bf(p0[r]);
      Pl[wid][4*g+r][16+l15]   = f2bf(p1[r]);
    }
    short8 pa = *(const short8*)&Pl[wid][l15][g*8];
    #pragma unroll
    for (int t = 0; t < 8; ++t) {
      short8 vb = *(const short8*)&Vt[cur][t*16+l15][g*8];
      o[t] = __builtin_amdgcn_mfma_f32_16x16x32_bf16(pa, vb, o[t], 0, 0, 0);
    }
    if (pf) {
      #pragma unroll
      for (int i = 0; i < 6; ++i) { int idx = i*256+tid; int row = idx/48, c4 = idx%48;
        ushort4 u; u.x=f2bf(kr[i].x); u.y=f2bf(kr[i].y); u.z=f2bf(kr[i].z); u.w=f2bf(kr[i].w);
        *(ushort4*)&Kl[cur^1][row][c4*4] = u; }
      #pragma unroll
      for (int i = 0; i < 4; ++i) { int idx = i*256+tid; int row = idx&31, c4 = idx>>5;
        Vt[cur^1][c4*4+0][row]=f2bf(vr[i].x); Vt[cur^1][c4*4+1][row]=f2bf(vr[i].y);
        Vt[cur^1][c4*4+2][row]=f2bf(vr[i].z); Vt[cur^1][c4*4+3][row]=f2bf(vr[i].w); }
    }
    __syncthreads();
    cur ^= 1;
  }
  #pragma unroll
  for (int r = 0; r < 4; ++r) {
    const int qg = q0w + 4*g + r;
    const float inv = 1.0f / l[r];
    #pragma unroll
    for (int t = 0; t < 8; ++t)
      O[((b*S_+qg)*H_ + h)*DV_ + t*16 + l15] = o[t][r] * inv;
  }
}

extern "C" void kernel_launch(void* const* d_in, const int* in_sizes, int n_in,
                              void* d_out, int out_size, void* d_ws, size_t ws_size,
                              hipStream_t stream) {
  const float* q = (const float*)d_in[0];
  const float* k = (const float*)d_in[1];
  const float* v = (const float*)d_in[2];
  float* out = (float*)d_out;

  if (ws_size >= KG_BYTES + VG_BYTES) {
    unsigned short* Kg = (unsigned short*)d_ws;
    unsigned short* Vg = (unsigned short*)((char*)d_ws + KG_BYTES);
    prep_k<<<dim3((B_ * S_ * H_ * 48) / 256), dim3(256), 0, stream>>>(k, Kg);
    prep_v<<<dim3(B_ * H_ * 32), dim3(256), 0, stream>>>(v, Vg);
    mla_fwd<<<dim3(512), dim3(256), 0, stream>>>(q, Kg, Vg, out);
  } else {
    dim3 grid(S_ / 64, B_ * H_);
    mla_fwd_fb<<<grid, dim3(256), 0, stream>>>(q, k, v, out);
  }
}